// Round 1
// 530.392 us; speedup vs baseline: 1.0035x; 1.0035x over previous
//
#include <hip/hip_runtime.h>
#include <math.h>

// Shapes fixed by reference: B=8, K=8, C=256, H=W=64 -> HW=4096 = 1024 float4/plane.
#define B_DIM 8
#define K_DIM 8
#define C_DIM 256
#define HW4   1024   // float4 elements per (b,k,c) plane

// ---------------------------------------------------------------------------
// Kernel 1: similarity reduction. One block per (b,c,k) plane pair:
//   sims[(b*C+c)*K + k] = 2 * <CT_bc, CR_bkc> / ||CR_bkc||
// 16384 blocks x 256 threads; each thread loads 4 float4 from each stream.
// All 8 loads are issued before any use -> 8 dwordx4 in flight per thread.
// Consecutive blocks (k=0..7) share the same CT plane -> L2/L3-hot.
// ---------------------------------------------------------------------------
__global__ __launch_bounds__(256, 4)
void dfs_sim(const float4* __restrict__ CR,
             const float4* __restrict__ CT,
             float* __restrict__ sims)
{
    const int bid = blockIdx.x;
    const int k   = bid & 7;             // k fastest: CT plane shared by 8 consecutive blocks
    const int bc  = bid >> 3;            // b*C + c
    const int b   = bc >> 8;
    const int c   = bc & 255;
    const int t   = threadIdx.x;

    const float4* __restrict__ ctp = CT + (size_t)bc * HW4;
    const float4* __restrict__ crp = CR + (size_t)((b * K_DIM + k) * C_DIM + c) * HW4;

    float4 a[4], r[4];
#pragma unroll
    for (int i = 0; i < 4; ++i) {
        a[i] = ctp[t + i * 256];
        r[i] = crp[t + i * 256];
    }
    float d = 0.f, s = 0.f;
#pragma unroll
    for (int i = 0; i < 4; ++i) {
        d = fmaf(a[i].x, r[i].x, d); d = fmaf(a[i].y, r[i].y, d);
        d = fmaf(a[i].z, r[i].z, d); d = fmaf(a[i].w, r[i].w, d);
        s = fmaf(r[i].x, r[i].x, s); s = fmaf(r[i].y, r[i].y, s);
        s = fmaf(r[i].z, r[i].z, s); s = fmaf(r[i].w, r[i].w, s);
    }

    // Wave butterfly (64 lanes), then 4-wave LDS combine.
#pragma unroll
    for (int off = 32; off >= 1; off >>= 1) {
        d += __shfl_xor(d, off, 64);
        s += __shfl_xor(s, off, 64);
    }
    __shared__ float rd[4], rs[4];
    const int wave = t >> 6, lane = t & 63;
    if (lane == 0) { rd[wave] = d; rs[wave] = s; }
    __syncthreads();
    if (t == 0) {
        const float dd = rd[0] + rd[1] + rd[2] + rd[3];
        const float ss = rs[0] + rs[1] + rs[2] + rs[3];
        sims[bid] = 2.0f * dd / sqrtf(ss);   // sim * 2.0 temperature
    }
}

// ---------------------------------------------------------------------------
// Kernel 2: softmax over K + weighted sum of IR planes. One block per (b,c):
// 2048 blocks x 256 threads x 4 float4. Softmax computed redundantly per
// thread from the 8 (wave-uniform -> scalar-loaded) sims: ZERO barriers,
// zero LDS -- pure streaming with 8 independent loads in flight per step.
// ---------------------------------------------------------------------------
__global__ __launch_bounds__(256, 4)
void dfs_mix(const float4* __restrict__ IR,
             const float* __restrict__ sims,
             float4* __restrict__ out)
{
    const int bc = blockIdx.x;           // b*C + c
    const int b  = bc >> 8;
    const int c  = bc & 255;
    const int t  = threadIdx.x;

    float si[K_DIM];
#pragma unroll
    for (int j = 0; j < K_DIM; ++j) si[j] = sims[bc * K_DIM + j];
    float m = si[0];
#pragma unroll
    for (int j = 1; j < K_DIM; ++j) m = fmaxf(m, si[j]);
    float w[K_DIM];
    float sum = 0.f;
#pragma unroll
    for (int j = 0; j < K_DIM; ++j) { w[j] = expf(si[j] - m); sum += w[j]; }
    const float inv = 1.0f / sum;
#pragma unroll
    for (int j = 0; j < K_DIM; ++j) w[j] *= inv;

    const size_t plane0  = (size_t)(b * K_DIM * C_DIM + c) * HW4;  // k=0 plane
    const size_t kstride = (size_t)C_DIM * HW4;
    const size_t obase   = (size_t)bc * HW4;

#pragma unroll
    for (int i = 0; i < 4; ++i) {
        const int off = t + i * 256;
        float4 v[K_DIM];
#pragma unroll
        for (int j = 0; j < K_DIM; ++j) v[j] = IR[plane0 + j * kstride + off];
        float4 acc = make_float4(0.f, 0.f, 0.f, 0.f);
#pragma unroll
        for (int j = 0; j < K_DIM; ++j) {
            acc.x = fmaf(w[j], v[j].x, acc.x);
            acc.y = fmaf(w[j], v[j].y, acc.y);
            acc.z = fmaf(w[j], v[j].z, acc.z);
            acc.w = fmaf(w[j], v[j].w, acc.w);
        }
        out[obase + off] = acc;
    }
}

extern "C" void kernel_launch(void* const* d_in, const int* in_sizes, int n_in,
                              void* d_out, int out_size, void* d_ws, size_t ws_size,
                              hipStream_t stream) {
    const float4* IR = (const float4*)d_in[0];  // [B,K,C,H,W] fp32
    const float4* CR = (const float4*)d_in[1];  // [B,K,C,H,W] fp32
    const float4* CT = (const float4*)d_in[2];  // [B,C,H,W]   fp32
    float4* out      = (float4*)d_out;          // [B,C,H,W]   fp32
    float* sims      = (float*)d_ws;            // [B,C,K] = 64 KB staging

    dfs_sim<<<B_DIM * C_DIM * K_DIM, 256, 0, stream>>>(CR, CT, sims);
    dfs_mix<<<B_DIM * C_DIM, 256, 0, stream>>>(IR, sims, out);
}

// Round 3
// 520.575 us; speedup vs baseline: 1.0224x; 1.0189x over previous
//
#include <hip/hip_runtime.h>
#include <math.h>

// Shapes fixed by reference: B=8, K=8, C=256, H=W=64 -> HW=4096 = 1024 float4/plane.
#define B_DIM 8
#define K_DIM 8
#define C_DIM 256
#define HW4   1024   // float4 elements per (b,k,c) plane

// Native clang vector type: __builtin_nontemporal_load rejects
// HIP_vector_type<float,4>*, but accepts ext_vector_type pointers.
typedef float v4f __attribute__((ext_vector_type(4)));

__device__ __forceinline__ float4 nt_load4(const float4* p) {
    v4f v = __builtin_nontemporal_load(reinterpret_cast<const v4f*>(p));
    return make_float4(v.x, v.y, v.z, v.w);
}

// One block per (b,c): 2048 blocks x 256 threads (4 waves).
//
// Phase 1: wave w computes sim for k=w and k=w+4 over the full plane.
//   Per lane-iteration: 4 CT + 4 CR(k0) + 4 CR(k1) = 12 independent float4
//   loads issued before any FMA -> 48 VGPRs of load data in flight
//   (launch_bounds(256,4) gives a 128-VGPR budget so the compiler can keep
//   them live; round-0's VGPR_Count=32 proved the old kernel could not).
//   CT is read by all 4 waves -> L1-served after the first wave (16 KiB).
//   CR is single-use -> nontemporal.
//
// Phase 2: all 256 threads stream the 8 IR planes (nontemporal, 8 loads in
//   flight) with the softmax weights computed redundantly per thread from
//   LDS-broadcast sims. Two barriers total.
__global__ __launch_bounds__(256, 4)
void dfs_fused2(const float4* __restrict__ IR,
                const float4* __restrict__ CR,
                const float4* __restrict__ CT,
                float4* __restrict__ out)
{
    const int bc   = blockIdx.x;         // b*C + c
    const int b    = bc >> 8;
    const int c    = bc & 255;
    const int t    = threadIdx.x;        // 0..255
    const int wave = t >> 6;             // 0..3
    const int lane = t & 63;

    const size_t ct_base = (size_t)bc * HW4;

    // ---- Phase 1: this wave's two k's ----
    const int k0 = wave;
    const int k1 = wave + 4;
    const size_t cr0b = (size_t)((b * K_DIM + k0) * C_DIM + c) * HW4;
    const size_t cr1b = (size_t)((b * K_DIM + k1) * C_DIM + c) * HW4;

    float d0 = 0.f, s0 = 0.f, d1 = 0.f, s1 = 0.f;
#pragma unroll
    for (int i = 0; i < 4; ++i) {
        float4 a[4], r0[4], r1[4];
#pragma unroll
        for (int j = 0; j < 4; ++j) {
            const int off = lane + j * 64 + i * 256;
            a[j] = CT[ct_base + off];
        }
#pragma unroll
        for (int j = 0; j < 4; ++j) {
            const int off = lane + j * 64 + i * 256;
            r0[j] = nt_load4(&CR[cr0b + off]);
        }
#pragma unroll
        for (int j = 0; j < 4; ++j) {
            const int off = lane + j * 64 + i * 256;
            r1[j] = nt_load4(&CR[cr1b + off]);
        }
#pragma unroll
        for (int j = 0; j < 4; ++j) {
            d0 = fmaf(a[j].x, r0[j].x, d0); d0 = fmaf(a[j].y, r0[j].y, d0);
            d0 = fmaf(a[j].z, r0[j].z, d0); d0 = fmaf(a[j].w, r0[j].w, d0);
            s0 = fmaf(r0[j].x, r0[j].x, s0); s0 = fmaf(r0[j].y, r0[j].y, s0);
            s0 = fmaf(r0[j].z, r0[j].z, s0); s0 = fmaf(r0[j].w, r0[j].w, s0);
            d1 = fmaf(a[j].x, r1[j].x, d1); d1 = fmaf(a[j].y, r1[j].y, d1);
            d1 = fmaf(a[j].z, r1[j].z, d1); d1 = fmaf(a[j].w, r1[j].w, d1);
            s1 = fmaf(r1[j].x, r1[j].x, s1); s1 = fmaf(r1[j].y, r1[j].y, s1);
            s1 = fmaf(r1[j].w, r1[j].w, s1); s1 = fmaf(r1[j].z, r1[j].z, s1);
        }
    }

    // Wave butterfly: 4 scalars x 6 steps.
#pragma unroll
    for (int off = 32; off >= 1; off >>= 1) {
        d0 += __shfl_xor(d0, off, 64);
        s0 += __shfl_xor(s0, off, 64);
        d1 += __shfl_xor(d1, off, 64);
        s1 += __shfl_xor(s1, off, 64);
    }

    __shared__ float sd[K_DIM], ss[K_DIM], simv[K_DIM];
    if (lane == 0) {
        sd[k0] = d0; ss[k0] = s0;
        sd[k1] = d1; ss[k1] = s1;
    }
    __syncthreads();
    if (t < K_DIM) simv[t] = 2.0f * sd[t] / sqrtf(ss[t]);  // sim * 2.0 temperature
    __syncthreads();

    // Per-thread redundant softmax from LDS-broadcast sims (no more barriers).
    float si[K_DIM];
#pragma unroll
    for (int j = 0; j < K_DIM; ++j) si[j] = simv[j];
    float m = si[0];
#pragma unroll
    for (int j = 1; j < K_DIM; ++j) m = fmaxf(m, si[j]);
    float w[K_DIM];
    float sum = 0.f;
#pragma unroll
    for (int j = 0; j < K_DIM; ++j) { w[j] = expf(si[j] - m); sum += w[j]; }
    const float inv = 1.0f / sum;
#pragma unroll
    for (int j = 0; j < K_DIM; ++j) w[j] *= inv;

    // ---- Phase 2: weighted sum over the 8 IR planes ----
    const size_t plane0  = (size_t)(b * K_DIM * C_DIM + c) * HW4;  // k=0 plane
    const size_t kstride = (size_t)C_DIM * HW4;

#pragma unroll
    for (int i = 0; i < 4; ++i) {
        const int off = t + i * 256;
        float4 v[K_DIM];
#pragma unroll
        for (int j = 0; j < K_DIM; ++j)
            v[j] = nt_load4(&IR[plane0 + j * kstride + off]);
        float4 acc = make_float4(0.f, 0.f, 0.f, 0.f);
#pragma unroll
        for (int j = 0; j < K_DIM; ++j) {
            acc.x = fmaf(w[j], v[j].x, acc.x);
            acc.y = fmaf(w[j], v[j].y, acc.y);
            acc.z = fmaf(w[j], v[j].z, acc.z);
            acc.w = fmaf(w[j], v[j].w, acc.w);
        }
        out[ct_base + off] = acc;
    }
}

extern "C" void kernel_launch(void* const* d_in, const int* in_sizes, int n_in,
                              void* d_out, int out_size, void* d_ws, size_t ws_size,
                              hipStream_t stream) {
    const float4* IR = (const float4*)d_in[0];  // [B,K,C,H,W] fp32
    const float4* CR = (const float4*)d_in[1];  // [B,K,C,H,W] fp32
    const float4* CT = (const float4*)d_in[2];  // [B,C,H,W]   fp32
    float4* out      = (float4*)d_out;          // [B,C,H,W]   fp32

    dfs_fused2<<<B_DIM * C_DIM, 256, 0, stream>>>(IR, CR, CT, out);
}

// Round 5
// 512.873 us; speedup vs baseline: 1.0378x; 1.0150x over previous
//
#include <hip/hip_runtime.h>
#include <math.h>

// Shapes fixed by reference: B=8, K=8, C=256, H=W=64 -> HW=4096 = 1024 float4/plane.
#define B_DIM 8
#define K_DIM 8
#define C_DIM 256
#define HW4   1024   // float4 elements per (b,k,c) plane
#define NBLK  1024   // grid-exact: 4 blocks/CU on 256 CUs, 2 tiles per block

// Native clang vector type: __builtin_nontemporal_{load,store} rejects
// HIP_vector_type<float,4>*, but accepts ext_vector_type pointers.
typedef float v4f __attribute__((ext_vector_type(4)));

__device__ __forceinline__ float4 nt_load4(const float4* p) {
    v4f v = __builtin_nontemporal_load(reinterpret_cast<const v4f*>(p));
    return make_float4(v.x, v.y, v.z, v.w);
}
__device__ __forceinline__ void nt_store4(float4* p, float4 f) {
    v4f v; v.x = f.x; v.y = f.y; v.z = f.z; v.w = f.w;
    __builtin_nontemporal_store(v, reinterpret_cast<v4f*>(p));
}

// Grid-exact residency: 1024 blocks x 256 threads (4 waves), each block owns
// exactly TWO (b,c) tiles (bc = blockIdx and blockIdx+1024). With
// launch_bounds(256,4) (VGPR<=128) capacity is >=4 blocks/CU, so ALL blocks
// are resident from t=0, every block does identical work -> no scheduling
// tail (the suspected 1.3-1.5x inflation of the 2048-block version).
//
// Per tile:
//   Phase 1: wave w computes sim for k=w and k=w+4; 12 independent float4
//     loads in flight per lane-iter (4 CT + 4 CR(k0) + 4 CR(k1)). CT is
//     L1-reused across the 4 waves; CR is single-use -> nontemporal.
//   Reduction: butterfly + LDS; 2 barriers. The same 2 barriers order LDS
//     reuse across tiles (simv is register-copied before phase 2, and no
//     thread can pass tile-2's first barrier until all threads did so).
//   Phase 2: all 256 threads stream the 8 IR planes (nontemporal, 8 loads
//     in flight), weights recomputed per thread from LDS-broadcast sims.
__global__ __launch_bounds__(256, 4)
void dfs_fused3(const float4* __restrict__ IR,
                const float4* __restrict__ CR,
                const float4* __restrict__ CT,
                float4* __restrict__ out)
{
    const int t    = threadIdx.x;        // 0..255
    const int wave = t >> 6;             // 0..3
    const int lane = t & 63;

    __shared__ float sd[K_DIM], ss[K_DIM], simv[K_DIM];

#pragma unroll
    for (int tile = 0; tile < 2; ++tile) {
        const int bc = blockIdx.x + tile * NBLK;   // b*C + c
        const int b  = bc >> 8;
        const int c  = bc & 255;

        const size_t ct_base = (size_t)bc * HW4;

        // ---- Phase 1: this wave's two k's ----
        const int k0 = wave;
        const int k1 = wave + 4;
        const size_t cr0b = (size_t)((b * K_DIM + k0) * C_DIM + c) * HW4;
        const size_t cr1b = (size_t)((b * K_DIM + k1) * C_DIM + c) * HW4;

        float d0 = 0.f, s0 = 0.f, d1 = 0.f, s1 = 0.f;
#pragma unroll
        for (int i = 0; i < 4; ++i) {
            float4 a[4], r0[4], r1[4];
#pragma unroll
            for (int j = 0; j < 4; ++j) {
                const int off = lane + j * 64 + i * 256;
                a[j] = CT[ct_base + off];
            }
#pragma unroll
            for (int j = 0; j < 4; ++j) {
                const int off = lane + j * 64 + i * 256;
                r0[j] = nt_load4(&CR[cr0b + off]);
            }
#pragma unroll
            for (int j = 0; j < 4; ++j) {
                const int off = lane + j * 64 + i * 256;
                r1[j] = nt_load4(&CR[cr1b + off]);
            }
#pragma unroll
            for (int j = 0; j < 4; ++j) {
                d0 = fmaf(a[j].x, r0[j].x, d0); d0 = fmaf(a[j].y, r0[j].y, d0);
                d0 = fmaf(a[j].z, r0[j].z, d0); d0 = fmaf(a[j].w, r0[j].w, d0);
                s0 = fmaf(r0[j].x, r0[j].x, s0); s0 = fmaf(r0[j].y, r0[j].y, s0);
                s0 = fmaf(r0[j].z, r0[j].z, s0); s0 = fmaf(r0[j].w, r0[j].w, s0);
                d1 = fmaf(a[j].x, r1[j].x, d1); d1 = fmaf(a[j].y, r1[j].y, d1);
                d1 = fmaf(a[j].z, r1[j].z, d1); d1 = fmaf(a[j].w, r1[j].w, d1);
                s1 = fmaf(r1[j].x, r1[j].x, s1); s1 = fmaf(r1[j].y, r1[j].y, s1);
                s1 = fmaf(r1[j].z, r1[j].z, s1); s1 = fmaf(r1[j].w, r1[j].w, s1);
            }
        }

        // Wave butterfly: 4 scalars x 6 steps.
#pragma unroll
        for (int off = 32; off >= 1; off >>= 1) {
            d0 += __shfl_xor(d0, off, 64);
            s0 += __shfl_xor(s0, off, 64);
            d1 += __shfl_xor(d1, off, 64);
            s1 += __shfl_xor(s1, off, 64);
        }

        if (lane == 0) {
            sd[k0] = d0; ss[k0] = s0;
            sd[k1] = d1; ss[k1] = s1;
        }
        __syncthreads();
        if (t < K_DIM) simv[t] = 2.0f * sd[t] / sqrtf(ss[t]);  // sim * 2.0
        __syncthreads();

        // Per-thread redundant softmax from LDS-broadcast sims.
        float si[K_DIM];
#pragma unroll
        for (int j = 0; j < K_DIM; ++j) si[j] = simv[j];
        float m = si[0];
#pragma unroll
        for (int j = 1; j < K_DIM; ++j) m = fmaxf(m, si[j]);
        float w[K_DIM];
        float sum = 0.f;
#pragma unroll
        for (int j = 0; j < K_DIM; ++j) { w[j] = expf(si[j] - m); sum += w[j]; }
        const float inv = 1.0f / sum;
#pragma unroll
        for (int j = 0; j < K_DIM; ++j) w[j] *= inv;

        // ---- Phase 2: weighted sum over the 8 IR planes ----
        const size_t plane0  = (size_t)(b * K_DIM * C_DIM + c) * HW4;  // k=0
        const size_t kstride = (size_t)C_DIM * HW4;

#pragma unroll
        for (int i = 0; i < 4; ++i) {
            const int off = t + i * 256;
            float4 v[K_DIM];
#pragma unroll
            for (int j = 0; j < K_DIM; ++j)
                v[j] = nt_load4(&IR[plane0 + j * kstride + off]);
            float4 acc = make_float4(0.f, 0.f, 0.f, 0.f);
#pragma unroll
            for (int j = 0; j < K_DIM; ++j) {
                acc.x = fmaf(w[j], v[j].x, acc.x);
                acc.y = fmaf(w[j], v[j].y, acc.y);
                acc.z = fmaf(w[j], v[j].z, acc.z);
                acc.w = fmaf(w[j], v[j].w, acc.w);
            }
            nt_store4(&out[ct_base + off], acc);
        }
    }
}

extern "C" void kernel_launch(void* const* d_in, const int* in_sizes, int n_in,
                              void* d_out, int out_size, void* d_ws, size_t ws_size,
                              hipStream_t stream) {
    const float4* IR = (const float4*)d_in[0];  // [B,K,C,H,W] fp32
    const float4* CR = (const float4*)d_in[1];  // [B,K,C,H,W] fp32
    const float4* CT = (const float4*)d_in[2];  // [B,C,H,W]   fp32
    float4* out      = (float4*)d_out;          // [B,C,H,W]   fp32

    dfs_fused3<<<NBLK, 256, 0, stream>>>(IR, CR, CT, out);
}